// Round 7
// baseline (416.098 us; speedup 1.0000x reference)
//
#include <hip/hip_runtime.h>
#include <hip/hip_bf16.h>

typedef unsigned short ushort_t;
typedef float f32x4 __attribute__((ext_vector_type(4)));
typedef __bf16 bf16x8 __attribute__((ext_vector_type(8)));

typedef const __attribute__((address_space(1))) void* gptr_t;
typedef __attribute__((address_space(3))) void* sptr_t;

#define GLD16(g, l) __builtin_amdgcn_global_load_lds((gptr_t)(g), (sptr_t)(l), 16, 0, 0)

// ---------------------------------------------------------------------------
// Kernel 1: global sum of W (fp32 partials, double atomic) -> ws scalar
// ---------------------------------------------------------------------------
__global__ void sum_w_kernel(const float* __restrict__ W, double* __restrict__ out, int n4) {
    int i = blockIdx.x * blockDim.x + threadIdx.x;
    int stride = gridDim.x * blockDim.x;
    float s = 0.f;
    for (; i < n4; i += stride) {
        float4 v = ((const float4*)W)[i];
        s += (v.x + v.y) + (v.z + v.w);
    }
    #pragma unroll
    for (int off = 32; off > 0; off >>= 1) s += __shfl_down(s, off, 64);
    __shared__ float red[4];
    int t = threadIdx.x;
    if ((t & 63) == 0) red[t >> 6] = s;
    __syncthreads();
    if (t == 0) {
        float bs = red[0] + red[1] + red[2] + red[3];
        atomicAdd(out, (double)bs);
    }
}

// ---------------------------------------------------------------------------
// Kernel 2: quantize W -> bf16 {0,1}
// ---------------------------------------------------------------------------
__global__ void quant_w_kernel(const float* __restrict__ W, ushort_t* __restrict__ Wq,
                               const double* __restrict__ sumw, float inv_n, int n4) {
    float mean = (float)(*sumw) * inv_n;
    int i = blockIdx.x * blockDim.x + threadIdx.x;
    int stride = gridDim.x * blockDim.x;
    for (; i < n4; i += stride) {
        float4 v = ((const float4*)W)[i];
        ushort4 o;
        o.x = (v.x > mean) ? 0x3F80 : 0;
        o.y = (v.y > mean) ? 0x3F80 : 0;
        o.z = (v.z > mean) ? 0x3F80 : 0;
        o.w = (v.w > mean) ? 0x3F80 : 0;
        ((ushort4*)Wq)[i] = o;
    }
}

// ---------------------------------------------------------------------------
// Kernel 3: convert x -> bf16 (round-to-nearest)
// ---------------------------------------------------------------------------
__device__ __forceinline__ ushort_t f2bf(float f) {
    __hip_bfloat16 h = __float2bfloat16(f);
    return *(ushort_t*)&h;
}

__global__ void cvt_x_kernel(const float* __restrict__ x, ushort_t* __restrict__ xb, int n4) {
    int i = blockIdx.x * blockDim.x + threadIdx.x;
    int stride = gridDim.x * blockDim.x;
    for (; i < n4; i += stride) {
        float4 v = ((const float4*)x)[i];
        ushort4 o;
        o.x = f2bf(v.x);
        o.y = f2bf(v.y);
        o.z = f2bf(v.z);
        o.w = f2bf(v.w);
        ((ushort4*)xb)[i] = o;
    }
}

// ---------------------------------------------------------------------------
// Kernel 4: quantize b (single block; n = 4096)
// ---------------------------------------------------------------------------
__global__ void quant_b_kernel(const float* __restrict__ b, float* __restrict__ bq, int n) {
    int t = threadIdx.x;
    float s = 0.f;
    for (int i = t; i < n; i += 256) s += b[i];
    #pragma unroll
    for (int off = 32; off > 0; off >>= 1) s += __shfl_down(s, off, 64);
    __shared__ float red[4];
    if ((t & 63) == 0) red[t >> 6] = s;
    __syncthreads();
    float mean = (red[0] + red[1] + red[2] + red[3]) / (float)n;
    for (int i = t; i < n; i += 256) bq[i] = (b[i] > mean) ? 1.0f : 0.0f;
}

// ---------------------------------------------------------------------------
// Kernel 5: bf16 MFMA GEMM, 256x256 tile, BK=64, 8 waves (2Mx4N), 4 phases
// per K-tile, LDS->reg reads SOFTWARE-PIPELINED ONE PHASE AHEAD with counted
// lgkm waits, so each phase's ds_read drain overlaps the previous phase's
// MFMA (LDS port serves the queue autonomously once reads are issued).
//   Per tile t (buf P, next NP), stages: S3=B1(t+1)@P1, S4=A1(t+1)@P2,
//   S1=A0(t+2)@P3, S2=B0(t+2)@P4. Publication gate vmcnt(2) at P3-end forces
//   S1..S4 of t+1 (each >=1.3 phases old = latency covered), leaves S1(t+2).
//   P4 pre-reads a0,b0 of t+1 (post-gate). b0 regs parity-duplicated (B0A/B0B);
//   a0 dead after P2 so P4 overwrite is safe. 4 barriers/tile; never vmcnt(0)
//   or uncounted lgkm in-loop except the cheap P3 lgkmcnt(0).
//   C[M,N] = A[M,K] * B[N,K]^T
// LDS swizzle (full-granule): byte ^= ((byte>>3) & 0x70). Involution,
// row-preserving; 8 lanes/16B-granule = wave64 b128 floor (0 conflicts, R3).
// ---------------------------------------------------------------------------
#define PRIO1 __builtin_amdgcn_s_setprio(1)
#define PRIO0 __builtin_amdgcn_s_setprio(0)
#define BAR() __builtin_amdgcn_s_barrier()
#define WAITV4() asm volatile("s_waitcnt vmcnt(4)" ::: "memory")
#define WAITV2() asm volatile("s_waitcnt vmcnt(2)" ::: "memory")
#define WAITV0() asm volatile("s_waitcnt vmcnt(0)" ::: "memory")
#define LGKM_(n) asm volatile("s_waitcnt lgkmcnt(" #n ")" ::: "memory")
#define LGKMC(n) do { LGKM_(n); __builtin_amdgcn_sched_barrier(0); } while (0)
#define UNRL _Pragma("unroll")

__global__ __launch_bounds__(512, 2) void gemm_bf16_256(
        const ushort_t* __restrict__ A, const ushort_t* __restrict__ B,
        float* __restrict__ C, int M, int N, int K) {
    __shared__ ushort_t lds8[65536];   // 128 KiB: [buf][A 16K ushorts | B 16K ushorts]
    char* ldsc = (char*)lds8;

    int nbn = N >> 8;
    int nwg = gridDim.x;
    int bid = blockIdx.x;
    int cpx = nwg >> 3;
    int wg = (bid & 7) * cpx + (bid >> 3);   // XCD swizzle (nwg % 8 == 0)
    int tm = wg / nbn, tn = wg % nbn;

    int t = threadIdx.x;
    int w = t >> 6, l = t & 63;
    int wr = w >> 2, wc = w & 3;             // 2 M-waves x 4 N-waves
    int wrOff = wr * 8192;                   // 64 rows * 128 B
    int wcOff = wc * 4096;                   // 32 rows * 128 B

    // read-side lane offsets, full-granule swizzle folded in
    int baseL = ((l & 15) * 128) + ((l >> 4) * 16);
    int laneA0 = baseL ^ ((l & 7) << 4);     // K elems 0..31
    int laneA1 = laneA0 ^ 64;                // K elems 32..63 (bit6 flip pre-swz)

    // stage-side source offsets (inverse swizzle = same involution), 32-bit
    int offA[2][2], offB[2][2];
    UNRL
    for (int c = 0; c < 2; ++c) {
        int o = (t + c * 512) * 16;
        int os = o ^ ((o >> 3) & 0x70);
        int lr = os >> 7;
        int col = (os & 127) >> 1;
        UNRL
        for (int h = 0; h < 2; ++h) {
            offA[c][h] = ((lr >> 6) * 128 + h * 64 + (lr & 63)) * K + col;
            offB[c][h] = ((lr >> 5) * 64 + h * 32 + (lr & 31)) * K + col;
        }
    }

    const ushort_t* srcA = A + (size_t)tm * 256 * K;
    const ushort_t* srcB = B + (size_t)tn * 256 * K;

    f32x4 acc[8][4] = {};
    bf16x8 a0[4][2], a1[4][2], b0A[2][2], b0B[2][2], b1[2][2];

#define STAGE_A(P, H, KIDX) do { \
    GLD16(srcA + (size_t)offA[0][H] + (KIDX), ldsc + (P)*65536 + (H)*16384 + w*1024); \
    GLD16(srcA + (size_t)offA[1][H] + (KIDX), ldsc + (P)*65536 + (H)*16384 + 8192 + w*1024); \
} while (0)
#define STAGE_B(P, H, KIDX) do { \
    GLD16(srcB + (size_t)offB[0][H] + (KIDX), ldsc + (P)*65536 + 32768 + (H)*16384 + w*1024); \
    GLD16(srcB + (size_t)offB[1][H] + (KIDX), ldsc + (P)*65536 + 32768 + (H)*16384 + 8192 + w*1024); \
} while (0)
#define LOAD_A(AF, P, H) do { UNRL for (int f = 0; f < 4; ++f) { \
    AF[f][0] = *(const bf16x8*)(ldsc + (P)*65536 + (H)*16384 + wrOff + f*2048 + laneA0); \
    AF[f][1] = *(const bf16x8*)(ldsc + (P)*65536 + (H)*16384 + wrOff + f*2048 + laneA1); \
} } while (0)
#define LOAD_B(BF, P, H) do { UNRL for (int e = 0; e < 2; ++e) { \
    BF[e][0] = *(const bf16x8*)(ldsc + (P)*65536 + 32768 + (H)*16384 + wcOff + e*2048 + laneA0); \
    BF[e][1] = *(const bf16x8*)(ldsc + (P)*65536 + 32768 + (H)*16384 + wcOff + e*2048 + laneA1); \
} } while (0)
#define MFMA_Q(QM, QN, AF, BF) do { UNRL for (int f = 0; f < 4; ++f) UNRL for (int e = 0; e < 2; ++e) { \
    acc[(QM)*4+f][(QN)*2+e] = __builtin_amdgcn_mfma_f32_16x16x32_bf16(AF[f][0], BF[e][0], acc[(QM)*4+f][(QN)*2+e], 0, 0, 0); \
    acc[(QM)*4+f][(QN)*2+e] = __builtin_amdgcn_mfma_f32_16x16x32_bf16(AF[f][1], BF[e][1], acc[(QM)*4+f][(QN)*2+e], 0, 0, 0); \
} } while (0)

// Pipelined tile: reads for phase p issued in phase p-1; counted lgkm gates.
#define TILE(P, NP, B0C, B0N, K1, K2) do { \
    /* P1 */ \
    LOAD_B(b1, P, 1);                     STAGE_B(NP, 1, K1); \
    LGKMC(4); PRIO1; MFMA_Q(0, 0, a0, B0C); PRIO0; BAR(); \
    /* P2 */ \
    LOAD_A(a1, P, 1);                     STAGE_A(NP, 1, K1); \
    LGKMC(8); PRIO1; MFMA_Q(0, 1, a0, b1); PRIO0; BAR(); \
    /* P3 (publication gate for buf NP) */ \
                                          STAGE_A(P, 0, K2); \
    LGKMC(0); PRIO1; MFMA_Q(1, 1, a1, b1); PRIO0; WAITV2(); BAR(); \
    /* P4 (post-gate): pre-read next tile's a0,b0 from NP */ \
    LOAD_A(a0, NP, 0); LOAD_B(B0N, NP, 0); STAGE_B(P, 0, K2); \
    PRIO1; MFMA_Q(1, 0, a1, B0C); PRIO0; BAR(); \
} while (0)

    // prologue: tile0 fully into buf0; S1,S2 (A0,B0) of tile1 into buf1
    STAGE_A(0, 0, 0); STAGE_B(0, 0, 0); STAGE_B(0, 1, 0); STAGE_A(0, 1, 0);
    STAGE_A(1, 0, 64); STAGE_B(1, 0, 64);
    WAITV4();           // force tile0's 8 loads; tile1's 4 stay in flight
    BAR();
    LOAD_A(a0, 0, 0); LOAD_B(b0A, 0, 0);   // pre-read tile0 (P4-style)

    for (int kt = 0; kt < K; kt += 128) {
        int k1a = kt + 64;
        int k2a = (kt + 128 < K) ? kt + 128 : 0;   // wrapped: redundant, never read
        int k1b = k2a;
        int k2b = (kt + 192 < K) ? kt + 192 : 0;
        TILE(0, 1, b0A, b0B, k1a, k2a);
        TILE(1, 0, b0B, b0A, k1b, k2b);
    }

    WAITV0();  // drain trailing stages before epilogue

    // epilogue: C/D layout col = lane&15, row = (lane>>4)*4 + r
    int crow0 = tm * 256 + wr * 128 + (l >> 4) * 4;
    int ccol0 = tn * 256 + wc * 64 + (l & 15);
    UNRL
    for (int fm = 0; fm < 8; ++fm)
        UNRL
        for (int fn = 0; fn < 4; ++fn)
            UNRL
            for (int r = 0; r < 4; ++r)
                C[(size_t)(crow0 + fm * 16 + r) * N + (ccol0 + fn * 16)] = acc[fm][fn][r];
}

// ---------------------------------------------------------------------------
// Kernel 6: per-row normalize in-place: z = (z + bq - mean) / (sqrt(var_ddof1) + eps)
// ---------------------------------------------------------------------------
__device__ __forceinline__ float block_sum_256(float v, float* red) {
    #pragma unroll
    for (int off = 32; off > 0; off >>= 1) v += __shfl_down(v, off, 64);
    int t = threadIdx.x;
    __syncthreads();
    if ((t & 63) == 0) red[t >> 6] = v;
    __syncthreads();
    return red[0] + red[1] + red[2] + red[3];
}

__global__ void rownorm_kernel(float* __restrict__ z, const float* __restrict__ bq, int N) {
    __shared__ float red[4];
    int row = blockIdx.x;
    float* zr = z + (size_t)row * N;
    int t = threadIdx.x;

    float4 v[4];
    float s = 0.f;
    #pragma unroll
    for (int j = 0; j < 4; ++j) {
        int idx = t + j * 256;
        float4 a = ((const float4*)zr)[idx];
        float4 bb = ((const float4*)bq)[idx];
        a.x += bb.x; a.y += bb.y; a.z += bb.z; a.w += bb.w;
        v[j] = a;
        s += (a.x + a.y) + (a.z + a.w);
    }
    float total = block_sum_256(s, red);
    float mean = total * (1.0f / 4096.0f);

    float q = 0.f;
    #pragma unroll
    for (int j = 0; j < 4; ++j) {
        float dx = v[j].x - mean, dy = v[j].y - mean, dz = v[j].z - mean, dw = v[j].w - mean;
        q += (dx * dx + dy * dy) + (dz * dz + dw * dw);
    }
    float qtot = block_sum_256(q, red);
    float var = qtot * (1.0f / 4095.0f);
    float inv = 1.0f / (sqrtf(var) + 1e-8f);

    #pragma unroll
    for (int j = 0; j < 4; ++j) {
        int idx = t + j * 256;
        float4 o;
        o.x = (v[j].x - mean) * inv;
        o.y = (v[j].y - mean) * inv;
        o.z = (v[j].z - mean) * inv;
        o.w = (v[j].w - mean) * inv;
        ((float4*)zr)[idx] = o;
    }
}

// ---------------------------------------------------------------------------
extern "C" void kernel_launch(void* const* d_in, const int* in_sizes, int n_in,
                              void* d_out, int out_size, void* d_ws, size_t ws_size,
                              hipStream_t stream) {
    const float* x = (const float*)d_in[0];
    const float* W = (const float*)d_in[1];
    const float* b = (const float*)d_in[2];
    float* out = (float*)d_out;

    const int N = in_sizes[2];            // 4096 (OUT)
    const int K = in_sizes[1] / N;        // 4096 (IN)
    const int M = in_sizes[0] / K;        // 8192

    // workspace layout
    char* ws = (char*)d_ws;
    ushort_t* xb = (ushort_t*)ws;                                   // M*K bf16
    ushort_t* wq = (ushort_t*)(ws + (size_t)M * K * 2);             // N*K bf16
    float* bq = (float*)(ws + (size_t)M * K * 2 + (size_t)N * K * 2);  // N fp32
    double* sumw = (double*)(ws + (size_t)M * K * 2 + (size_t)N * K * 2 + (size_t)N * 4);

    hipMemsetAsync(sumw, 0, sizeof(double), stream);
    sum_w_kernel<<<1024, 256, 0, stream>>>(W, sumw, N * K / 4);
    quant_w_kernel<<<2048, 256, 0, stream>>>(W, wq, sumw, 1.0f / (float)((size_t)N * K), N * K / 4);
    cvt_x_kernel<<<2048, 256, 0, stream>>>(x, xb, M * K / 4);
    quant_b_kernel<<<1, 256, 0, stream>>>(b, bq, N);

    int grid = (M / 256) * (N / 256);
    gemm_bf16_256<<<grid, 512, 0, stream>>>(xb, wq, out, M, N, K);

    rownorm_kernel<<<M, 256, 0, stream>>>(out, bq, N);
}

// Round 8
// 338.437 us; speedup vs baseline: 1.2295x; 1.2295x over previous
//
#include <hip/hip_runtime.h>
#include <hip/hip_bf16.h>

typedef unsigned short ushort_t;
typedef float f32x4 __attribute__((ext_vector_type(4)));
typedef __bf16 bf16x8 __attribute__((ext_vector_type(8)));

typedef const __attribute__((address_space(1))) void* gptr_t;
typedef __attribute__((address_space(3))) void* sptr_t;

#define GLD16(g, l) __builtin_amdgcn_global_load_lds((gptr_t)(g), (sptr_t)(l), 16, 0, 0)

// ---------------------------------------------------------------------------
// Kernel 1: global sum of W (fp32 partials, double atomic) -> ws scalar
// ---------------------------------------------------------------------------
__global__ void sum_w_kernel(const float* __restrict__ W, double* __restrict__ out, int n4) {
    int i = blockIdx.x * blockDim.x + threadIdx.x;
    int stride = gridDim.x * blockDim.x;
    float s = 0.f;
    for (; i < n4; i += stride) {
        float4 v = ((const float4*)W)[i];
        s += (v.x + v.y) + (v.z + v.w);
    }
    #pragma unroll
    for (int off = 32; off > 0; off >>= 1) s += __shfl_down(s, off, 64);
    __shared__ float red[4];
    int t = threadIdx.x;
    if ((t & 63) == 0) red[t >> 6] = s;
    __syncthreads();
    if (t == 0) {
        float bs = red[0] + red[1] + red[2] + red[3];
        atomicAdd(out, (double)bs);
    }
}

// ---------------------------------------------------------------------------
// Kernel 2: quantize W -> bf16 {0,1}
// ---------------------------------------------------------------------------
__global__ void quant_w_kernel(const float* __restrict__ W, ushort_t* __restrict__ Wq,
                               const double* __restrict__ sumw, float inv_n, int n4) {
    float mean = (float)(*sumw) * inv_n;
    int i = blockIdx.x * blockDim.x + threadIdx.x;
    int stride = gridDim.x * blockDim.x;
    for (; i < n4; i += stride) {
        float4 v = ((const float4*)W)[i];
        ushort4 o;
        o.x = (v.x > mean) ? 0x3F80 : 0;
        o.y = (v.y > mean) ? 0x3F80 : 0;
        o.z = (v.z > mean) ? 0x3F80 : 0;
        o.w = (v.w > mean) ? 0x3F80 : 0;
        ((ushort4*)Wq)[i] = o;
    }
}

// ---------------------------------------------------------------------------
// Kernel 3: convert x -> bf16 (round-to-nearest)
// ---------------------------------------------------------------------------
__device__ __forceinline__ ushort_t f2bf(float f) {
    __hip_bfloat16 h = __float2bfloat16(f);
    return *(ushort_t*)&h;
}

__global__ void cvt_x_kernel(const float* __restrict__ x, ushort_t* __restrict__ xb, int n4) {
    int i = blockIdx.x * blockDim.x + threadIdx.x;
    int stride = gridDim.x * blockDim.x;
    for (; i < n4; i += stride) {
        float4 v = ((const float4*)x)[i];
        ushort4 o;
        o.x = f2bf(v.x);
        o.y = f2bf(v.y);
        o.z = f2bf(v.z);
        o.w = f2bf(v.w);
        ((ushort4*)xb)[i] = o;
    }
}

// ---------------------------------------------------------------------------
// Kernel 4: quantize b (single block; n = 4096)
// ---------------------------------------------------------------------------
__global__ void quant_b_kernel(const float* __restrict__ b, float* __restrict__ bq, int n) {
    int t = threadIdx.x;
    float s = 0.f;
    for (int i = t; i < n; i += 256) s += b[i];
    #pragma unroll
    for (int off = 32; off > 0; off >>= 1) s += __shfl_down(s, off, 64);
    __shared__ float red[4];
    if ((t & 63) == 0) red[t >> 6] = s;
    __syncthreads();
    float mean = (red[0] + red[1] + red[2] + red[3]) / (float)n;
    for (int i = t; i < n; i += 256) bq[i] = (b[i] > mean) ? 1.0f : 0.0f;
}

// ---------------------------------------------------------------------------
// Kernel 5: bf16 MFMA GEMM, 256x256 tile, BK=64, 8 waves (2Mx4N), 4 phases
// per K-tile. DEEP-PREFETCH schedule: stages spread ph1(A0'+B0'), ph2(B1'),
// ph3(A1'), all into the dead buffer; exactly TWO counted vmcnt gates/tile:
//   ph2-end vmcnt(6): forces only A1(t) (issued t-1.ph3, ~3 phases old ->
//                     latency fully covered), publishing it for ph3's reads.
//   ph4-end vmcnt(2): forces A0',B0',B1' (2.5-3.5 phases old -> free),
//                     leaves A1' in flight for the next tile's ph2-end gate.
// Never vmcnt(0), never a <2-phase-distance wait in the loop (R7 lesson:
// 1-phase distance < 900-cyc HBM latency = stall every gate).
// Each gate is followed by BAR so all waves' loads are published (per-wave
// vmcnt alone cannot gate cross-wave GLD16 data).
//   C[M,N] = A[M,K] * B[N,K]^T
// LDS swizzle (full-granule): byte ^= ((byte>>3) & 0x70). Involution,
// row-preserving; 8 lanes/16B-granule = wave64 b128 floor (0 conflicts, R3).
// ---------------------------------------------------------------------------
#define PRIO1 __builtin_amdgcn_s_setprio(1)
#define PRIO0 __builtin_amdgcn_s_setprio(0)
#define BAR() __builtin_amdgcn_s_barrier()
#define WAITV6() asm volatile("s_waitcnt vmcnt(6)" ::: "memory")
#define WAITV2() asm volatile("s_waitcnt vmcnt(2)" ::: "memory")
#define WAITV0() asm volatile("s_waitcnt vmcnt(0)" ::: "memory")
#define LGKM0() do { asm volatile("s_waitcnt lgkmcnt(0)" ::: "memory"); \
                     __builtin_amdgcn_sched_barrier(0); } while (0)
#define UNRL _Pragma("unroll")

__global__ __launch_bounds__(512, 2) void gemm_bf16_256(
        const ushort_t* __restrict__ A, const ushort_t* __restrict__ B,
        float* __restrict__ C, int M, int N, int K) {
    __shared__ ushort_t lds8[65536];   // 128 KiB: [buf][A 16K ushorts | B 16K ushorts]
    char* ldsc = (char*)lds8;

    int nbn = N >> 8;
    int nwg = gridDim.x;
    int bid = blockIdx.x;
    int cpx = nwg >> 3;
    int wg = (bid & 7) * cpx + (bid >> 3);   // XCD swizzle (nwg % 8 == 0)
    int tm = wg / nbn, tn = wg % nbn;

    int t = threadIdx.x;
    int w = t >> 6, l = t & 63;
    int wr = w >> 2, wc = w & 3;             // 2 M-waves x 4 N-waves
    int wrOff = wr * 8192;                   // 64 rows * 128 B
    int wcOff = wc * 4096;                   // 32 rows * 128 B

    // read-side lane offsets, full-granule swizzle folded in
    int baseL = ((l & 15) * 128) + ((l >> 4) * 16);
    int laneA0 = baseL ^ ((l & 7) << 4);     // K elems 0..31
    int laneA1 = laneA0 ^ 64;                // K elems 32..63 (bit6 flip pre-swz)

    // stage-side source offsets (inverse swizzle = same involution), 32-bit
    int offA[2][2], offB[2][2];
    UNRL
    for (int c = 0; c < 2; ++c) {
        int o = (t + c * 512) * 16;
        int os = o ^ ((o >> 3) & 0x70);
        int lr = os >> 7;
        int col = (os & 127) >> 1;
        UNRL
        for (int h = 0; h < 2; ++h) {
            offA[c][h] = ((lr >> 6) * 128 + h * 64 + (lr & 63)) * K + col;
            offB[c][h] = ((lr >> 5) * 64 + h * 32 + (lr & 31)) * K + col;
        }
    }

    const ushort_t* srcA = A + (size_t)tm * 256 * K;
    const ushort_t* srcB = B + (size_t)tn * 256 * K;

    f32x4 acc[8][4] = {};
    bf16x8 af[4][2], bf0[2][2], bf1[2][2];

#define STAGE_A(P, H, KIDX) do { \
    GLD16(srcA + (size_t)offA[0][H] + (KIDX), ldsc + (P)*65536 + (H)*16384 + w*1024); \
    GLD16(srcA + (size_t)offA[1][H] + (KIDX), ldsc + (P)*65536 + (H)*16384 + 8192 + w*1024); \
} while (0)
#define STAGE_B(P, H, KIDX) do { \
    GLD16(srcB + (size_t)offB[0][H] + (KIDX), ldsc + (P)*65536 + 32768 + (H)*16384 + w*1024); \
    GLD16(srcB + (size_t)offB[1][H] + (KIDX), ldsc + (P)*65536 + 32768 + (H)*16384 + 8192 + w*1024); \
} while (0)
#define LOAD_AF(P, H) do { UNRL for (int f = 0; f < 4; ++f) { \
    af[f][0] = *(const bf16x8*)(ldsc + (P)*65536 + (H)*16384 + wrOff + f*2048 + laneA0); \
    af[f][1] = *(const bf16x8*)(ldsc + (P)*65536 + (H)*16384 + wrOff + f*2048 + laneA1); \
} } while (0)
#define LOAD_BF(BF, P, H) do { UNRL for (int e = 0; e < 2; ++e) { \
    BF[e][0] = *(const bf16x8*)(ldsc + (P)*65536 + 32768 + (H)*16384 + wcOff + e*2048 + laneA0); \
    BF[e][1] = *(const bf16x8*)(ldsc + (P)*65536 + 32768 + (H)*16384 + wcOff + e*2048 + laneA1); \
} } while (0)
#define MFMA_Q(QM, QN, BF) do { UNRL for (int f = 0; f < 4; ++f) UNRL for (int e = 0; e < 2; ++e) { \
    acc[(QM)*4+f][(QN)*2+e] = __builtin_amdgcn_mfma_f32_16x16x32_bf16(af[f][0], BF[e][0], acc[(QM)*4+f][(QN)*2+e], 0, 0, 0); \
    acc[(QM)*4+f][(QN)*2+e] = __builtin_amdgcn_mfma_f32_16x16x32_bf16(af[f][1], BF[e][1], acc[(QM)*4+f][(QN)*2+e], 0, 0, 0); \
} } while (0)

// Deep-prefetch tile: stages spread across ph1-ph3 (all into dead buf PN),
// two counted gates (ph2-end vmcnt6 publishes A1; ph4-end vmcnt2 publishes
// A0',B0',B1'). No intra-tile read-vs-write hazards (reads hit P only).
#define TILE(P, PN, KTN) do { \
    /* ph1: reads a0,b0 | stage A0',B0' */ \
    LOAD_AF(P, 0); LOAD_BF(bf0, P, 0); STAGE_A(PN, 0, KTN); STAGE_B(PN, 0, KTN); \
    LGKM0(); PRIO1; MFMA_Q(0, 0, bf0); PRIO0; BAR(); \
    /* ph2: reads b1 | stage B1' */ \
    LOAD_BF(bf1, P, 1);                STAGE_B(PN, 1, KTN); \
    LGKM0(); PRIO1; MFMA_Q(0, 1, bf1); PRIO0; WAITV6(); BAR(); \
    /* ph3: reads a1 (A1 just published) | stage A1' */ \
    LOAD_AF(P, 1);                     STAGE_A(PN, 1, KTN); \
    LGKM0(); PRIO1; MFMA_Q(1, 1, bf1); PRIO0; BAR(); \
    /* ph4: no reads */ \
    PRIO1; MFMA_Q(1, 0, bf0); PRIO0; WAITV2(); BAR(); \
} while (0)

    // prologue: stage tile 0 fully into buf0, drain once (outside main loop)
    STAGE_A(0, 0, 0); STAGE_B(0, 0, 0); STAGE_B(0, 1, 0); STAGE_A(0, 1, 0);
    WAITV0();
    BAR();

    for (int kt = 0; kt < K; kt += 128) {
        int kn1 = kt + 64;
        int kn2 = (kt + 128 < K) ? kt + 128 : 0;   // wrap: redundant, never read
        TILE(0, 1, kn1);
        TILE(1, 0, kn2);
    }

    WAITV0();  // drain trailing stages before epilogue

    // epilogue: C/D layout col = lane&15, row = (lane>>4)*4 + r
    int crow0 = tm * 256 + wr * 128 + (l >> 4) * 4;
    int ccol0 = tn * 256 + wc * 64 + (l & 15);
    UNRL
    for (int fm = 0; fm < 8; ++fm)
        UNRL
        for (int fn = 0; fn < 4; ++fn)
            UNRL
            for (int r = 0; r < 4; ++r)
                C[(size_t)(crow0 + fm * 16 + r) * N + (ccol0 + fn * 16)] = acc[fm][fn][r];
}

// ---------------------------------------------------------------------------
// Kernel 6: per-row normalize in-place: z = (z + bq - mean) / (sqrt(var_ddof1) + eps)
// ---------------------------------------------------------------------------
__device__ __forceinline__ float block_sum_256(float v, float* red) {
    #pragma unroll
    for (int off = 32; off > 0; off >>= 1) v += __shfl_down(v, off, 64);
    int t = threadIdx.x;
    __syncthreads();
    if ((t & 63) == 0) red[t >> 6] = v;
    __syncthreads();
    return red[0] + red[1] + red[2] + red[3];
}

__global__ void rownorm_kernel(float* __restrict__ z, const float* __restrict__ bq, int N) {
    __shared__ float red[4];
    int row = blockIdx.x;
    float* zr = z + (size_t)row * N;
    int t = threadIdx.x;

    float4 v[4];
    float s = 0.f;
    #pragma unroll
    for (int j = 0; j < 4; ++j) {
        int idx = t + j * 256;
        float4 a = ((const float4*)zr)[idx];
        float4 bb = ((const float4*)bq)[idx];
        a.x += bb.x; a.y += bb.y; a.z += bb.z; a.w += bb.w;
        v[j] = a;
        s += (a.x + a.y) + (a.z + a.w);
    }
    float total = block_sum_256(s, red);
    float mean = total * (1.0f / 4096.0f);

    float q = 0.f;
    #pragma unroll
    for (int j = 0; j < 4; ++j) {
        float dx = v[j].x - mean, dy = v[j].y - mean, dz = v[j].z - mean, dw = v[j].w - mean;
        q += (dx * dx + dy * dy) + (dz * dz + dw * dw);
    }
    float qtot = block_sum_256(q, red);
    float var = qtot * (1.0f / 4095.0f);
    float inv = 1.0f / (sqrtf(var) + 1e-8f);

    #pragma unroll
    for (int j = 0; j < 4; ++j) {
        int idx = t + j * 256;
        float4 o;
        o.x = (v[j].x - mean) * inv;
        o.y = (v[j].y - mean) * inv;
        o.z = (v[j].z - mean) * inv;
        o.w = (v[j].w - mean) * inv;
        ((float4*)zr)[idx] = o;
    }
}

// ---------------------------------------------------------------------------
extern "C" void kernel_launch(void* const* d_in, const int* in_sizes, int n_in,
                              void* d_out, int out_size, void* d_ws, size_t ws_size,
                              hipStream_t stream) {
    const float* x = (const float*)d_in[0];
    const float* W = (const float*)d_in[1];
    const float* b = (const float*)d_in[2];
    float* out = (float*)d_out;

    const int N = in_sizes[2];            // 4096 (OUT)
    const int K = in_sizes[1] / N;        // 4096 (IN)
    const int M = in_sizes[0] / K;        // 8192

    // workspace layout
    char* ws = (char*)d_ws;
    ushort_t* xb = (ushort_t*)ws;                                   // M*K bf16
    ushort_t* wq = (ushort_t*)(ws + (size_t)M * K * 2);             // N*K bf16
    float* bq = (float*)(ws + (size_t)M * K * 2 + (size_t)N * K * 2);  // N fp32
    double* sumw = (double*)(ws + (size_t)M * K * 2 + (size_t)N * K * 2 + (size_t)N * 4);

    hipMemsetAsync(sumw, 0, sizeof(double), stream);
    sum_w_kernel<<<1024, 256, 0, stream>>>(W, sumw, N * K / 4);
    quant_w_kernel<<<2048, 256, 0, stream>>>(W, wq, sumw, 1.0f / (float)((size_t)N * K), N * K / 4);
    cvt_x_kernel<<<2048, 256, 0, stream>>>(x, xb, M * K / 4);
    quant_b_kernel<<<1, 256, 0, stream>>>(b, bq, N);

    int grid = (M / 256) * (N / 256);
    gemm_bf16_256<<<grid, 512, 0, stream>>>(xb, wq, out, M, N, K);

    rownorm_kernel<<<M, 256, 0, stream>>>(out, bq, N);
}